// Round 2
// baseline (226.181 us; speedup 1.0000x reference)
//
#include <hip/hip_runtime.h>
#include <stdint.h>

#define TOKENS 8192
#define IN_F   4096
#define OUT_F  4096

#define BM 128
#define BN 128
#define BK 64   // bytes of K per tile step (64 int8)

typedef int v4i __attribute__((ext_vector_type(4)));

#define GLOBAL_AS __attribute__((address_space(1)))
#define LDS_AS    __attribute__((address_space(3)))

// ---------------- pack x: int32 -> int8 ----------------
// Each thread: read 4 int32 (16B coalesced), write 4 bytes (coalesced).
__global__ __launch_bounds__(256) void pack_x_kernel(const int* __restrict__ x32,
                                                     uint8_t* __restrict__ x8) {
  int t = blockIdx.x * 256 + threadIdx.x;          // one thread per 4 elements
  const int4 v = ((const int4*)x32)[t];
  uint32_t p = (uint32_t)(v.x & 0xFF)
             | ((uint32_t)(v.y & 0xFF) << 8)
             | ((uint32_t)(v.z & 0xFF) << 16)
             | ((uint32_t)(v.w & 0xFF) << 24);
  ((uint32_t*)x8)[t] = p;
}

// -------- pack + transpose W: int32 [K][N] -> int8 WT [N][K] --------
// 64x64 tile per block. Thread gathers 16 k-values for one n (reads are
// 64B-coalesced across the quarter-wave for each j), writes 16B contiguous.
__global__ __launch_bounds__(256) void packT_w_kernel(const int* __restrict__ w32,
                                                      uint8_t* __restrict__ wt8) {
  int tn = (blockIdx.x & 63) * 64;   // n-tile (OUT_F/64 = 64 tiles)
  int tk = (blockIdx.x >> 6) * 64;   // k-tile (IN_F/64 = 64 tiles)
  int t = threadIdx.x;
  int n  = tn + (t >> 2);
  int k0 = tk + (t & 3) * 16;
  uint32_t words[4];
#pragma unroll
  for (int w = 0; w < 4; ++w) {
    uint32_t acc = 0;
#pragma unroll
    for (int j = 0; j < 4; ++j) {
      int val = w32[(size_t)(k0 + w * 4 + j) * OUT_F + n];
      acc |= (uint32_t)(val & 0xFF) << (8 * j);
    }
    words[w] = acc;
  }
  uint4 o = make_uint4(words[0], words[1], words[2], words[3]);
  *(uint4*)(wt8 + (size_t)n * IN_F + k0) = o;
}

// ---------------- int8 GEMM (m97-style structure) ----------------
// A: [M][K] int8 (k-contig), BT: [N][K] int8 (k-contig).
// 128x128 tile, 4 waves (2x2), each wave 64x64 via 4x4 frags of 16x16x64.
__global__ __launch_bounds__(256) void gemm_i8_kernel(const uint8_t* __restrict__ A,
                                                      const uint8_t* __restrict__ BT,
                                                      const int* __restrict__ bias,
                                                      const float* __restrict__ scales,
                                                      int* __restrict__ out) {
  __shared__ __align__(16) uint8_t As[BM * BK];   // 8 KB, linear [row][64]
  __shared__ __align__(16) uint8_t Bs[BN * BK];   // 8 KB

  // XCD-aware swizzle: 2048 blocks, 2048 % 8 == 0 -> simple bijective remap
  int bid = blockIdx.x;
  int swz = (bid & 7) * 256 + (bid >> 3);
  int bm = swz >> 5;        // 0..63  (TOKENS/BM)
  int bn = swz & 31;        // 0..31  (OUT_F/BN)

  const int t    = threadIdx.x;
  const int lane = t & 63;
  const int w    = t >> 6;
  const int wr   = w >> 1, wc = w & 1;

  const int rowq = t >> 2;         // 0..63  row within a 64-row half tile
  const int colb = (t & 3) * 16;   // 16B chunk within 64B row

  const size_t aBase = (size_t)(bm * BM) * IN_F;
  const size_t bBase = (size_t)(bn * BN) * IN_F;

  v4i acc[4][4];
  const v4i vzero = {0, 0, 0, 0};
#pragma unroll
  for (int i = 0; i < 4; ++i)
#pragma unroll
    for (int j = 0; j < 4; ++j) acc[i][j] = vzero;

  const int fr   = lane & 15;     // frag row (A) / col (B) / col (C)
  const int fq   = lane >> 4;     // k-group 0..3
  const int aoff = fq * 16;       // byte offset of k-chunk within row

  for (int k0 = 0; k0 < IN_F; k0 += BK) {
    // ---- stage A and B tiles (global -> LDS direct, 16B per lane) ----
#pragma unroll
    for (int i = 0; i < 2; ++i) {
      const uint8_t* ga = A + aBase + (size_t)(i * 64 + rowq) * IN_F + k0 + colb;
      __builtin_amdgcn_global_load_lds((const GLOBAL_AS void*)ga,
                                       (LDS_AS void*)(As + i * 4096 + t * 16),
                                       16, 0, 0);
      const uint8_t* gb = BT + bBase + (size_t)(i * 64 + rowq) * IN_F + k0 + colb;
      __builtin_amdgcn_global_load_lds((const GLOBAL_AS void*)gb,
                                       (LDS_AS void*)(Bs + i * 4096 + t * 16),
                                       16, 0, 0);
    }
    __syncthreads();   // compiler drains vmcnt before barrier -> LDS valid

    // ---- fragments + 16 MFMA ----
    v4i af[4], bf[4];
#pragma unroll
    for (int m = 0; m < 4; ++m)
      af[m] = *(const v4i*)(As + (wr * 64 + m * 16 + fr) * BK + aoff);
#pragma unroll
    for (int n = 0; n < 4; ++n)
      bf[n] = *(const v4i*)(Bs + (wc * 64 + n * 16 + fr) * BK + aoff);
#pragma unroll
    for (int m = 0; m < 4; ++m)
#pragma unroll
      for (int n = 0; n < 4; ++n)
        acc[m][n] = __builtin_amdgcn_mfma_i32_16x16x64_i8(af[m], bf[n], acc[m][n], 0, 0, 0);
    __syncthreads();   // protect LDS before next stage
  }

  // ---- epilogue: (acc + bias) * scale / 0.05, clip, trunc-to-int ----
  // Output buffer is INT32 (harness materializes int8 reference output as i32).
  // C/D layout (16x16, dtype-independent): col = lane&15, row = (lane>>4)*4 + r
#pragma unroll
  for (int n = 0; n < 4; ++n) {
    const int gn  = bn * BN + wc * 64 + n * 16 + fr;
    const int bsv = bias[gn];
    const float sc = scales[gn] * 20.0f;   // == scales/0.05 to fp32 precision
#pragma unroll
    for (int m = 0; m < 4; ++m) {
      const int gm0 = bm * BM + wr * 64 + m * 16 + fq * 4;
#pragma unroll
      for (int r = 0; r < 4; ++r) {
        float g = (float)(acc[m][n][r] + bsv) * sc;
        g = fminf(fmaxf(g, -128.0f), 127.0f);
        out[(size_t)(gm0 + r) * OUT_F + gn] = (int)g;  // trunc toward 0, stored as int32
      }
    }
  }
}

extern "C" void kernel_launch(void* const* d_in, const int* in_sizes, int n_in,
                              void* d_out, int out_size, void* d_ws, size_t ws_size,
                              hipStream_t stream) {
  const int*   x32    = (const int*)d_in[0];    // [TOKENS][IN_F], values in [-128,127]
  const int*   w32    = (const int*)d_in[1];    // [IN_F][OUT_F]
  const int*   bias   = (const int*)d_in[2];    // [OUT_F]
  const float* scales = (const float*)d_in[3];  // [OUT_F]
  int* out = (int*)d_out;                       // int8 result values stored as int32

  uint8_t* x8  = (uint8_t*)d_ws;                              // 32 MB
  uint8_t* wt8 = (uint8_t*)d_ws + (size_t)TOKENS * IN_F;      // 16 MB

  // pack x: TOKENS*IN_F/4 threads
  pack_x_kernel<<<(TOKENS * IN_F / 4) / 256, 256, 0, stream>>>(x32, x8);
  // pack+transpose W: (OUT_F/64)*(IN_F/64) = 4096 blocks
  packT_w_kernel<<<(OUT_F / 64) * (IN_F / 64), 256, 0, stream>>>(w32, wt8);
  // GEMM: 64*32 = 2048 blocks
  gemm_i8_kernel<<<(TOKENS / BM) * (OUT_F / BN), 256, 0, stream>>>(x8, wt8, bias, scales, out);
}

// Round 3
// 194.780 us; speedup vs baseline: 1.1612x; 1.1612x over previous
//
#include <hip/hip_runtime.h>
#include <stdint.h>

#define TOKENS 8192
#define IN_F   4096
#define OUT_F  4096

#define BM 256
#define BN 256
#define BK 64                 // bytes of K per slice (64 int8)
#define NK (IN_F / BK)        // 64 slices
#define THREADS 512

typedef int v4i __attribute__((ext_vector_type(4)));

#define GLOBAL_AS __attribute__((address_space(1)))
#define LDS_AS    __attribute__((address_space(3)))

// ---------------- pack x: int32 -> int8 ----------------
__global__ __launch_bounds__(256) void pack_x_kernel(const int* __restrict__ x32,
                                                     uint8_t* __restrict__ x8) {
  int t = blockIdx.x * 256 + threadIdx.x;
  const int4 v = ((const int4*)x32)[t];
  uint32_t p = (uint32_t)(v.x & 0xFF)
             | ((uint32_t)(v.y & 0xFF) << 8)
             | ((uint32_t)(v.z & 0xFF) << 16)
             | ((uint32_t)(v.w & 0xFF) << 24);
  ((uint32_t*)x8)[t] = p;
}

// -------- pack + transpose W: int32 [K][N] -> int8 WT [N][K] --------
__global__ __launch_bounds__(256) void packT_w_kernel(const int* __restrict__ w32,
                                                      uint8_t* __restrict__ wt8) {
  int tn = (blockIdx.x & 63) * 64;
  int tk = (blockIdx.x >> 6) * 64;
  int t = threadIdx.x;
  int n  = tn + (t >> 2);
  int k0 = tk + (t & 3) * 16;
  uint32_t words[4];
#pragma unroll
  for (int w = 0; w < 4; ++w) {
    uint32_t acc = 0;
#pragma unroll
    for (int j = 0; j < 4; ++j) {
      int val = w32[(size_t)(k0 + w * 4 + j) * OUT_F + n];
      acc |= (uint32_t)(val & 0xFF) << (8 * j);
    }
    words[w] = acc;
  }
  uint4 o = make_uint4(words[0], words[1], words[2], words[3]);
  *(uint4*)(wt8 + (size_t)n * IN_F + k0) = o;
}

// ---------------- int8 GEMM: 256x256 tile, 4-slot ring, counted vmcnt ----------------
// A: [M][K] int8, BT: [N][K] int8. 8 waves (2Mx4N), wave tile 128x64,
// 8x4 frags of mfma_i32_16x16x64_i8, acc = 128 VGPRs.
__global__ __launch_bounds__(THREADS, 2) void gemm_i8_kernel(const uint8_t* __restrict__ A,
                                                             const uint8_t* __restrict__ BT,
                                                             const int* __restrict__ bias,
                                                             const float* __restrict__ scales,
                                                             int* __restrict__ out) {
  // Ring of 4 K-slices. Slot: A half0 @0, A half1 @8192, B half0 @16384, B half1 @24576.
  __shared__ __align__(16) uint8_t lds[4 * 32768];   // 128 KiB

  const int t    = threadIdx.x;
  const int lane = t & 63;
  const int w    = t >> 6;
  const int wr   = w >> 2;     // 0..1  (row half of 256)
  const int wc   = w & 3;      // 0..3  (64-col slice)
  const int fr   = lane & 15;
  const int fq   = lane >> 4;

  // XCD-aware bijective swizzle: 512 blocks, 512 % 8 == 0
  int bid = blockIdx.x;
  int swz = (bid & 7) * 64 + (bid >> 3);
  int bm = swz >> 4;           // 0..31
  int bn = swz & 15;           // 0..15

  // ---- staging: pre-swizzled global source, linear LDS dest (rule #21) ----
  // chunk involution sigma(l) = l ^ ((l>>3)&7) on 16B chunks within 8KiB half-tile
  const int lsz  = t ^ ((t >> 3) & 7);
  const int srow = lsz >> 2;            // 0..127 row within half-tile
  const int scol = (lsz & 3) * 16;      // byte col within 64B row
  const size_t gA0 = (size_t)(bm * BM + srow) * IN_F + scol;
  const size_t gA1 = gA0 + (size_t)128 * IN_F;
  const size_t gB0 = (size_t)(bn * BN + srow) * IN_F + scol;
  const size_t gB1 = gB0 + (size_t)128 * IN_F;
  const int ldst = t * 16;              // linear dest within 8KiB half region

  auto stage = [&](int j) {
    uint8_t* sb = lds + (j & 3) * 32768;
    const int k0 = j * BK;
    __builtin_amdgcn_global_load_lds((const GLOBAL_AS void*)(A  + gA0 + k0),
                                     (LDS_AS void*)(sb + ldst),           16, 0, 0);
    __builtin_amdgcn_global_load_lds((const GLOBAL_AS void*)(A  + gA1 + k0),
                                     (LDS_AS void*)(sb + 8192  + ldst),   16, 0, 0);
    __builtin_amdgcn_global_load_lds((const GLOBAL_AS void*)(BT + gB0 + k0),
                                     (LDS_AS void*)(sb + 16384 + ldst),   16, 0, 0);
    __builtin_amdgcn_global_load_lds((const GLOBAL_AS void*)(BT + gB1 + k0),
                                     (LDS_AS void*)(sb + 24576 + ldst),   16, 0, 0);
  };

  // ---- fragment read offsets (slot-relative), swizzled to match staging ----
  int aoff[8], boff[4];
#pragma unroll
  for (int m = 0; m < 8; ++m) {
    int row = wr * 128 + m * 16 + fr;       // 0..255
    int half = row >> 7, rl = row & 127;
    int b = rl * 64 + fq * 16;
    b ^= ((rl >> 1) & 7) << 4;              // sigma on read side
    aoff[m] = half * 8192 + b;
  }
#pragma unroll
  for (int n = 0; n < 4; ++n) {
    int row = wc * 64 + n * 16 + fr;        // 0..255
    int half = row >> 7, rl = row & 127;
    int b = rl * 64 + fq * 16;
    b ^= ((rl >> 1) & 7) << 4;
    boff[n] = 16384 + half * 8192 + b;
  }

  v4i acc[8][4];
  const v4i vzero = {0, 0, 0, 0};
#pragma unroll
  for (int m = 0; m < 8; ++m)
#pragma unroll
    for (int n = 0; n < 4; ++n) acc[m][n] = vzero;

  auto compute = [&](int i) {
    const uint8_t* sb = lds + (i & 3) * 32768;
    v4i bf[4], af[4];
#pragma unroll
    for (int n = 0; n < 4; ++n) bf[n] = *(const v4i*)(sb + boff[n]);
#pragma unroll
    for (int m = 0; m < 4; ++m) af[m] = *(const v4i*)(sb + aoff[m]);
    __builtin_amdgcn_s_setprio(1);
#pragma unroll
    for (int m = 0; m < 4; ++m)
#pragma unroll
      for (int n = 0; n < 4; ++n)
        acc[m][n] = __builtin_amdgcn_mfma_i32_16x16x64_i8(af[m], bf[n], acc[m][n], 0, 0, 0);
    __builtin_amdgcn_s_setprio(0);
#pragma unroll
    for (int m = 0; m < 4; ++m) af[m] = *(const v4i*)(sb + aoff[4 + m]);
    __builtin_amdgcn_s_setprio(1);
#pragma unroll
    for (int m = 0; m < 4; ++m)
#pragma unroll
      for (int n = 0; n < 4; ++n)
        acc[4 + m][n] = __builtin_amdgcn_mfma_i32_16x16x64_i8(af[m], bf[n], acc[4 + m][n], 0, 0, 0);
    __builtin_amdgcn_s_setprio(0);
  };

  // Pipeline: prefetch depth 3; vmcnt counts 4 loads/slice/wave.
  // Iter i: vmcnt(8) -> slice i landed (only i+1,i+2 in flight); barrier;
  // stage slice i+3 into slot (i+3)%4 = (i-1)%4 (last read iter i-1, drained
  // by every wave before this barrier); compute slice i.
  stage(0); stage(1); stage(2);

#define ITER(i, VM, DOSTAGE)                                       \
  asm volatile("s_waitcnt vmcnt(" #VM ")" ::: "memory");           \
  asm volatile("s_barrier" ::: "memory");                          \
  if (DOSTAGE) stage((i) + 3);                                     \
  __builtin_amdgcn_sched_barrier(0);                               \
  compute(i);

  for (int i = 0; i < NK - 3; ++i) {
    ITER(i, 8, true)
  }
  ITER(NK - 3, 8, false)
  ITER(NK - 2, 4, false)
  ITER(NK - 1, 0, false)
#undef ITER

  // ---- epilogue: (acc + bias) * scale * 20, clip, trunc; int32 out ----
  // C/D layout (16x16): col = lane&15, row = (lane>>4)*4 + r
#pragma unroll
  for (int n = 0; n < 4; ++n) {
    const int gn  = bn * BN + wc * 64 + n * 16 + fr;
    const int bsv = bias[gn];
    const float sc = scales[gn] * 20.0f;
#pragma unroll
    for (int m = 0; m < 8; ++m) {
      const int gm0 = bm * BM + wr * 128 + m * 16 + fq * 4;
#pragma unroll
      for (int r = 0; r < 4; ++r) {
        float g = (float)(acc[m][n][r] + bsv) * sc;
        g = fminf(fmaxf(g, -128.0f), 127.0f);
        out[(size_t)(gm0 + r) * OUT_F + gn] = (int)g;
      }
    }
  }
}

extern "C" void kernel_launch(void* const* d_in, const int* in_sizes, int n_in,
                              void* d_out, int out_size, void* d_ws, size_t ws_size,
                              hipStream_t stream) {
  const int*   x32    = (const int*)d_in[0];
  const int*   w32    = (const int*)d_in[1];
  const int*   bias   = (const int*)d_in[2];
  const float* scales = (const float*)d_in[3];
  int* out = (int*)d_out;

  uint8_t* x8  = (uint8_t*)d_ws;                              // 32 MB
  uint8_t* wt8 = (uint8_t*)d_ws + (size_t)TOKENS * IN_F;      // 16 MB

  pack_x_kernel<<<(TOKENS * IN_F / 4) / 256, 256, 0, stream>>>(x32, x8);
  packT_w_kernel<<<(OUT_F / 64) * (IN_F / 64), 256, 0, stream>>>(w32, wt8);
  gemm_i8_kernel<<<(TOKENS / BM) * (OUT_F / BN), THREADS, 0, stream>>>(x8, wt8, bias, scales, out);
}